// Round 12
// baseline (55.093 us; speedup 1.0000x reference)
//
#include <hip/hip_runtime.h>

#define NQ 14

// ================= single-source closed-form machinery =================
// Ring C = CNOT(0->1), CNOT(1->2), ..., CNOT(n-1->0) applied in that order.
// Heisenberg pullback of Z_w through the ring -> Z-string mask (phase-free):
template <int N>
__host__ __device__ constexpr unsigned ringZ(unsigned w) {
  unsigned z = 1u << w;
  for (int c = N - 1; c >= 0; --c) {
    const int t = (c + 1) % N;
    if ((z >> t) & 1u) z ^= 1u << c;
  }
  return z;
}

// Chain contraction for one (output mask m, boundary bits beta, beta').
//   a[j],b[j] = cos,sin(theta_j/2)   (theta = x + w0)
//   c1[j],s1[j] = cos,sin(w1_j)      (full angle)
// E_w = sum over (beta,beta') of chainE(...).
template <int N, typename T>
__host__ __device__ constexpr T chainE(const T* a, const T* b, const T* c1, const T* s1,
                                       unsigned m, unsigned beta, unsigned betap) {
  const T p0 = beta ? b[1] : a[1], p1 = beta ? a[1] : b[1];
  const T q0 = betap ? b[1] : a[1], q1 = betap ? a[1] : b[1];
  T v00 = p0 * q0, v01 = p0 * q1, v10 = p1 * q0, v11 = p1 * q1;
  {
    const bool mb = ((m >> 1) & 1u) != 0;
    const T kd = mb ? c1[1] : T(1);
    const T kn = mb ? -c1[1] : T(1);
    const T ko = mb ? -s1[1] : T(0);
    v00 *= kd; v01 *= ko; v10 *= ko; v11 *= kn;
  }
#pragma unroll
  for (int j = 2; j < N; ++j) {
    const T aj = a[j], bj = b[j];
    const T t00 = aj * v00 + bj * v10, t01 = aj * v01 + bj * v11;
    const T t10 = aj * v10 + bj * v00, t11 = aj * v11 + bj * v01;
    T u00 = aj * t00 + bj * t01, u01 = aj * t01 + bj * t00;
    T u10 = aj * t10 + bj * t11, u11 = aj * t11 + bj * t10;
    const bool mb = ((m >> j) & 1u) != 0;
    const T kd = mb ? c1[j] : T(1);
    const T kn = mb ? -c1[j] : T(1);
    const T ko = mb ? -s1[j] : T(0);
    v00 = u00 * kd; v01 = u01 * ko; v10 = u10 * ko; v11 = u11 * kn;
  }
  // closure at site 0: g_0 = g^beta, g'_0 = g'^betap
  T S;
  if (m & 1u) {
    const T c = c1[0], s = s1[0];
    const bool same = (beta == betap);
    const T k00 = same ? (beta ? -c : c) : -s;
    const T k11 = same ? (beta ? c : -c) : -s;
    const T k01 = !same ? (beta ? -c : c) : -s;
    const T k10 = !same ? (beta ? c : -c) : -s;
    S = v00 * k00 + v01 * k01 + v10 * k10 + v11 * k11;
  } else {
    S = (beta == betap) ? (v00 + v11) : (v01 + v10);
  }
  const T f0 = beta ? b[0] : a[0];
  const T f1 = betap ? b[0] : a[0];
  return f0 * f1 * S;
}

// ================= compile-time verification vs brute force =================
constexpr double c_sin(double x) {
  constexpr double PI = 3.14159265358979323846;
  while (x > PI) x -= 2.0 * PI;
  while (x < -PI) x += 2.0 * PI;
  double term = x, sum = x;
  const double x2 = x * x;
  for (int k = 1; k <= 15; ++k) { term *= -x2 / double((2 * k) * (2 * k + 1)); sum += term; }
  return sum;
}
constexpr double c_cos(double x) { return c_sin(x + 1.5707963267948966); }

// Independent brute-force simulation of the REFERENCE circuit (bit j = wire j),
// compared against the SAME chainE/ringZ the device uses.
template <int N>
constexpr bool verify(unsigned seed) {
  constexpr int SZ = 1 << N;
  double xa[N] = {}, w0[N] = {}, w1[N] = {};
  unsigned s = seed;
  for (int j = 0; j < N; ++j) { s = s * 1664525u + 1013904223u; xa[j] = 6.283185307179586 * double((s >> 8) & 0xFFFFu) / 65536.0; }
  for (int j = 0; j < N; ++j) { s = s * 1664525u + 1013904223u; w0[j] = 6.283185307179586 * double((s >> 8) & 0xFFFFu) / 65536.0; }
  for (int j = 0; j < N; ++j) { s = s * 1664525u + 1013904223u; w1[j] = 6.283185307179586 * double((s >> 8) & 0xFFFFu) / 65536.0; }
  double st[SZ] = {};
  st[0] = 1.0;
  for (int pass = 0; pass < 3; ++pass) {
    const double* ang = pass == 0 ? xa : (pass == 1 ? w0 : w1);
    for (int w = 0; w < N; ++w) {  // RY layer
      const double ch = c_cos(0.5 * ang[w]), sh = c_sin(0.5 * ang[w]);
      for (int i = 0; i < SZ; ++i) {
        if ((i >> w) & 1) continue;
        const int j2 = i | (1 << w);
        const double A0 = st[i], A1 = st[j2];
        st[i] = ch * A0 - sh * A1;
        st[j2] = sh * A0 + ch * A1;
      }
    }
    if (pass >= 1) {  // CNOT ring, w -> w+1 mod N, in order
      for (int w = 0; w < N; ++w) {
        const int c = w, t = (w + 1) % N;
        for (int i = 0; i < SZ; ++i) {
          if (((i >> c) & 1) && !((i >> t) & 1)) {
            const int j2 = i ^ (1 << t);
            const double tmp = st[i];
            st[i] = st[j2];
            st[j2] = tmp;
          }
        }
      }
    }
  }
  double a[N] = {}, b[N] = {}, c1[N] = {}, s1[N] = {};
  for (int j = 0; j < N; ++j) {
    a[j] = c_cos(0.5 * (xa[j] + w0[j]));
    b[j] = c_sin(0.5 * (xa[j] + w0[j]));
    c1[j] = c_cos(w1[j]);
    s1[j] = c_sin(w1[j]);
  }
  for (int w = 0; w < N; ++w) {
    double Eref = 0.0;
    for (int i = 0; i < SZ; ++i) Eref += st[i] * st[i] * (((i >> w) & 1) ? -1.0 : 1.0);
    double E = 0.0;
    for (unsigned bb = 0; bb < 4; ++bb)
      E += chainE<N, double>(a, b, c1, s1, ringZ<N>((unsigned)w), bb >> 1, bb & 1u);
    const double d = E > Eref ? E - Eref : Eref - E;
    if (d > 1e-9) return false;
  }
  return true;
}
static_assert(verify<3>(1u), "closed form != brute force at n=3");
static_assert(verify<4>(1234u), "closed form != brute force at n=4");
static_assert(verify<5>(98765u), "closed form != brute force at n=5");
static_assert(verify<6>(555u), "closed form != brute force at n=6");
static_assert(verify<5>(31337u), "closed form != brute force at n=5 (seed 2)");

// masks for n=14, from the same single-source ringZ
struct MWTab { unsigned v[NQ]; };
constexpr MWTab mk_mw() {
  MWTab t{};
  for (int w = 0; w < NQ; ++w) t.v[w] = ringZ<NQ>((unsigned)w);
  return t;
}
constexpr MWTab MWT = mk_mw();

// ================= device kernel =================
// Block = 256 threads = 4 batch elements x 64 lanes.
// Lane role: w = lane>>2 (output wire, <14), bb = lane&3 = (beta,beta').
// NOTE: __sinf/__cosf only (value-returning) — no pointer-output __sincosf,
// so no private-stack/scratch allocation for the dispatch.
__global__ __launch_bounds__(256) void qnn_kernel(const float* __restrict__ x,
                                                  const float* __restrict__ wts,
                                                  float* __restrict__ out, int B) {
  __shared__ float sa[4][NQ], sb[4][NQ], sc[NQ], ss[NQ];
  const unsigned tid = threadIdx.x;
  const unsigned eL = tid >> 6, lane = tid & 63u;
  const int e = blockIdx.x * 4 + (int)eL;

  if (lane < NQ && e < B) {  // per-element theta/2 trigs
    const float th = 0.5f * (x[e * NQ + lane] + wts[lane]);
    sb[eL][lane] = __sinf(th);
    sa[eL][lane] = __cosf(th);
  }
  if (tid >= 64 && tid < 64 + NQ) {  // per-block w1 full-angle trigs
    const unsigned j = tid - 64;
    const float aw = wts[NQ + j];
    ss[j] = __sinf(aw);
    sc[j] = __cosf(aw);
  }
  __syncthreads();

  const unsigned w = lane >> 2, bb = lane & 3u;
  float E = 0.0f;
  if (w < NQ && e < B) {
    E = chainE<NQ, float>(sa[eL], sb[eL], sc, ss, MWT.v[w], bb >> 1, bb & 1u);
  }
  // sum the 4 boundary cases
  E += __shfl_xor(E, 1, 64);
  E += __shfl_xor(E, 2, 64);
  if (w < NQ && bb == 0 && e < B) out[e * NQ + w] = E;
}

extern "C" void kernel_launch(void* const* d_in, const int* in_sizes, int n_in,
                              void* d_out, int out_size, void* d_ws, size_t ws_size,
                              hipStream_t stream) {
  const float* x = (const float*)d_in[0];        // (B, 14) fp32
  const float* weights = (const float*)d_in[1];  // (2, 14) fp32
  float* out = (float*)d_out;                    // (B, 14) fp32
  const int B = in_sizes[0] / NQ;
  const int grid = (B + 3) / 4;
  qnn_kernel<<<grid, 256, 0, stream>>>(x, weights, out, B);
}